// Round 1
// baseline (185.143 us; speedup 1.0000x reference)
//
#include <hip/hip_runtime.h>

#define BN 2048
#define DD 128

typedef __attribute__((ext_vector_type(8))) short bf8;
typedef __attribute__((ext_vector_type(16))) float f16v;

__device__ __forceinline__ short bf16rne(float f) {
    unsigned u = __float_as_uint(f);
    u = (u + 0x7FFFu + ((u >> 16) & 1u)) >> 16;
    return (short)u;
}

// Flash-style attention with query-row masking (reference's row-mask bug).
// Block: 64 q-rows, 4 waves = (row-tile rt) x (key-half kh). BK=128 keys/iter.
// No-max softmax: p = exp2(s * log2e/sqrt(d)); masked rows: p = exp2(0) = 1.
__launch_bounds__(256, 2)
__global__ void attn_kernel(const float* __restrict__ Q,
                            const float* __restrict__ K,
                            const float* __restrict__ V,
                            const int* __restrict__ VL,
                            float* __restrict__ O) {
    // XOR-swizzled LDS, 16B groups: group g of row r stored at (g&8)|((g^r)&7).
    __shared__ short sK[128 * 128];   // [key r][d]      32 KB
    __shared__ short sV[128 * 128];   // [d][key k]      32 KB (transposed)
    __shared__ short sP[4 * 32 * 64]; // per-wave P      16 KB
    // total 80 KB -> 2 blocks/CU

    const int tid  = threadIdx.x;
    const int wave = tid >> 6;
    const int lane = tid & 63;
    const int lw   = lane & 31;
    const int lh   = lane >> 5;
    const int rt   = wave & 1;   // q row-tile (32 rows)
    const int kh   = wave >> 1;  // key half (64 keys of the 128-key tile)

    // decode: same-batch blocks land on one XCD (assumes XCD = blockIdx % 8),
    // and the 2 co-resident blocks per CU share a batch for L2 reuse.
    const int L  = blockIdx.x;
    const int b  = (L & 7) | (((L >> 3) & 1) << 3);
    const int qt = L >> 4;
    const int q0 = qt * 64;

    const int vlen = VL[b];

    constexpr float SCL2 = 1.4426950408889634f * 0.08838834764831845f; // log2e/sqrt(128)

    // per-reg masked scale: masked row -> 0 -> p = exp2(0) = 1 (uniform attn)
    float sclm[16];
    #pragma unroll
    for (int reg = 0; reg < 16; ++reg) {
        int row = (reg & 3) + 8 * (reg >> 2) + 4 * lh;
        int qg = q0 + rt * 32 + row;
        sclm[reg] = (qg >= vlen) ? 0.0f : SCL2;
    }

    // Q fragments (A operand: A[m=lane&31][k=(lane>>5)*8+j]), once per block
    const size_t qoff = ((size_t)b * BN + q0 + rt * 32 + lw) * DD;
    bf8 qfrag[8];
    #pragma unroll
    for (int ks = 0; ks < 8; ++ks) {
        int d0 = ks * 16 + lh * 8;
        float4 f0 = *(const float4*)(Q + qoff + d0);
        float4 f1 = *(const float4*)(Q + qoff + d0 + 4);
        bf8 w;
        w[0] = bf16rne(f0.x); w[1] = bf16rne(f0.y);
        w[2] = bf16rne(f0.z); w[3] = bf16rne(f0.w);
        w[4] = bf16rne(f1.x); w[5] = bf16rne(f1.y);
        w[6] = bf16rne(f1.z); w[7] = bf16rne(f1.w);
        qfrag[ks] = w;
    }

    f16v oacc[4] = {};   // O accumulator: 4 d-tiles of 32, rows = wave's 32 q-rows
    float l[16];
    #pragma unroll
    for (int i = 0; i < 16; ++i) l[i] = 0.0f;

    const int pbase = wave * (32 * 64);

    for (int it = 0; it < 16; ++it) {
        const int kb = it * 128;

        // ---- stage K tile (bf16, swizzled): coalesced f32 loads
        {
            int g  = tid & 15;
            int r0 = tid >> 4;
            #pragma unroll
            for (int i = 0; i < 8; ++i) {
                int r = r0 + 16 * i;
                const float* src = K + ((size_t)b * BN + kb + r) * DD + g * 8;
                float4 f0 = *(const float4*)(src);
                float4 f1 = *(const float4*)(src + 4);
                bf8 w;
                w[0] = bf16rne(f0.x); w[1] = bf16rne(f0.y);
                w[2] = bf16rne(f0.z); w[3] = bf16rne(f0.w);
                w[4] = bf16rne(f1.x); w[5] = bf16rne(f1.y);
                w[6] = bf16rne(f1.z); w[7] = bf16rne(f1.w);
                int sg = (g & 8) | ((g ^ r) & 7);
                *(bf8*)&sK[r * 128 + sg * 8] = w;
            }
        }
        // ---- stage V tile transposed sV[d][k]: 8k x 4d register block per task
        {
            int dq  = tid & 31;
            int kg0 = tid >> 5;
            #pragma unroll
            for (int i = 0; i < 2; ++i) {
                int kg = kg0 + 8 * i;
                float vr[32];
                #pragma unroll
                for (int j = 0; j < 8; ++j) {
                    float4 t = *(const float4*)(V + ((size_t)b * BN + kb + kg * 8 + j) * DD + dq * 4);
                    vr[j * 4 + 0] = t.x; vr[j * 4 + 1] = t.y;
                    vr[j * 4 + 2] = t.z; vr[j * 4 + 3] = t.w;
                }
                #pragma unroll
                for (int c = 0; c < 4; ++c) {
                    int d = dq * 4 + c;
                    bf8 w;
                    #pragma unroll
                    for (int j = 0; j < 8; ++j) w[j] = bf16rne(vr[j * 4 + c]);
                    int sg = (kg & 8) | ((kg ^ d) & 7);
                    *(bf8*)&sV[d * 128 + sg * 8] = w;
                }
            }
        }
        __syncthreads();

        // ---- S = Q K^T for this wave's 32 rows x 64 keys (2 col-tiles)
        f16v s0 = {}, s1 = {};
        #pragma unroll
        for (int ks = 0; ks < 8; ++ks) {
            int g  = ks * 2 + lh;
            int r0 = kh * 64 + lw;
            int sgA = (g & 8) | ((g ^ r0) & 7);
            bf8 b0 = *(const bf8*)&sK[r0 * 128 + sgA * 8];
            s0 = __builtin_amdgcn_mfma_f32_32x32x16_bf16(qfrag[ks], b0, s0, 0, 0, 0);
            int r1 = r0 + 32;
            int sgB = (g & 8) | ((g ^ r1) & 7);
            bf8 b1 = *(const bf8*)&sK[r1 * 128 + sgB * 8];
            s1 = __builtin_amdgcn_mfma_f32_32x32x16_bf16(qfrag[ks], b1, s1, 0, 0, 0);
        }

        // ---- p = exp2(s*sclm); accumulate l; write P (bf16) to LDS
        #pragma unroll
        for (int reg = 0; reg < 16; ++reg) {
            float p0 = __builtin_amdgcn_exp2f(s0[reg] * sclm[reg]);
            float p1 = __builtin_amdgcn_exp2f(s1[reg] * sclm[reg]);
            l[reg] += p0 + p1;
            int row = (reg & 3) + 8 * (reg >> 2) + 4 * lh;
            int g0 = lw >> 3;
            sP[pbase + row * 64 + ((g0 ^ row) & 7) * 8 + (lw & 7)] = bf16rne(p0);
            int g1 = 4 + (lw >> 3);
            sP[pbase + row * 64 + ((g1 ^ row) & 7) * 8 + (lw & 7)] = bf16rne(p1);
        }

        // ---- O += P V (wave's own 64 keys)
        #pragma unroll
        for (int ks = 0; ks < 4; ++ks) {
            int gk  = ks * 2 + lh;
            int sgp = (gk ^ lw) & 7;
            bf8 pa = *(const bf8*)&sP[pbase + lw * 64 + sgp * 8];
            #pragma unroll
            for (int ot = 0; ot < 4; ++ot) {
                int d   = ot * 32 + lw;
                int gv  = kh * 8 + ks * 2 + lh;
                int sgv = (gv & 8) | ((gv ^ d) & 7);
                bf8 vb = *(const bf8*)&sV[d * 128 + sgv * 8];
                oacc[ot] = __builtin_amdgcn_mfma_f32_32x32x16_bf16(pa, vb, oacc[ot], 0, 0, 0);
            }
        }
        __syncthreads();
    }

    // ---- epilogue: combine key-halves (kh=1 publishes, kh=0 reduces+stores)
    float* oSh = (float*)sK;   // [rt][32][128] f32
    float* lSh = (float*)sV;   // [rt][16][64]  f32
    if (kh == 1) {
        #pragma unroll
        for (int ot = 0; ot < 4; ++ot) {
            #pragma unroll
            for (int reg = 0; reg < 16; ++reg) {
                int row = (reg & 3) + 8 * (reg >> 2) + 4 * lh;
                oSh[rt * 4096 + row * 128 + ot * 32 + lw] = oacc[ot][reg];
            }
        }
        #pragma unroll
        for (int reg = 0; reg < 16; ++reg)
            lSh[rt * 1024 + reg * 64 + lane] = l[reg];
    }
    __syncthreads();
    if (kh == 0) {
        #pragma unroll
        for (int reg = 0; reg < 16; ++reg)
            l[reg] += lSh[rt * 1024 + reg * 64 + lane];
        #pragma unroll
        for (int reg = 0; reg < 16; ++reg) {
            float t = l[reg];
            t += __shfl_xor(t, 1, 64);
            t += __shfl_xor(t, 2, 64);
            t += __shfl_xor(t, 4, 64);
            t += __shfl_xor(t, 8, 64);
            t += __shfl_xor(t, 16, 64);
            l[reg] = t;
        }
        #pragma unroll
        for (int ot = 0; ot < 4; ++ot) {
            #pragma unroll
            for (int reg = 0; reg < 16; ++reg) {
                int row = (reg & 3) + 8 * (reg >> 2) + 4 * lh;
                float val = oacc[ot][reg] + oSh[rt * 4096 + row * 128 + ot * 32 + lw];
                val /= l[reg];
                O[((size_t)b * BN + q0 + rt * 32 + row) * DD + ot * 32 + lw] = val;
            }
        }
    }
}

extern "C" void kernel_launch(void* const* d_in, const int* in_sizes, int n_in,
                              void* d_out, int out_size, void* d_ws, size_t ws_size,
                              hipStream_t stream) {
    const float* Q  = (const float*)d_in[0];
    const float* K  = (const float*)d_in[1];
    const float* V  = (const float*)d_in[2];
    const int*   VL = (const int*)d_in[3];
    float* O = (float*)d_out;
    attn_kernel<<<512, 256, 0, stream>>>(Q, K, V, VL, O);
}

// Round 2
// 148.166 us; speedup vs baseline: 1.2496x; 1.2496x over previous
//
#include <hip/hip_runtime.h>

#define BN 2048
#define DD 128

typedef __attribute__((ext_vector_type(8))) short bf8;
typedef __attribute__((ext_vector_type(16))) float f16v;

__device__ __forceinline__ short bf16rne(float f) {
    unsigned u = __float_as_uint(f);
    u = (u + 0x7FFFu + ((u >> 16) & 1u)) >> 16;
    return (short)u;
}

__device__ __forceinline__ bf8 cvt8(float4 f0, float4 f1) {
    bf8 w;
    w[0] = bf16rne(f0.x); w[1] = bf16rne(f0.y);
    w[2] = bf16rne(f0.z); w[3] = bf16rne(f0.w);
    w[4] = bf16rne(f1.x); w[5] = bf16rne(f1.y);
    w[6] = bf16rne(f1.z); w[7] = bf16rne(f1.w);
    return w;
}

// 16B-per-lane direct global->LDS DMA (no VGPR round trip, no VALU convert)
__device__ __forceinline__ void dma16(const void* gsrc, void* ldst) {
    __builtin_amdgcn_global_load_lds(
        (const __attribute__((address_space(1))) void*)gsrc,
        (__attribute__((address_space(3))) void*)ldst,
        16, 0, 0);
}

// wave copies its contiguous 8KB slice of a 32KB tile image
__device__ __forceinline__ void dma_tile(short* lds, const short* g, int wave, int lane) {
    const char* gp = (const char*)g + wave * 8192 + lane * 16;
    char* lp = (char*)lds + wave * 8192 + lane * 16;
    #pragma unroll
    for (int c = 0; c < 8; ++c)
        dma16(gp + c * 1024, lp + c * 1024);
}

// ---------------- pre-pass: build swizzled bf16 LDS images in d_ws ----------
// K image (b,it): dst[r*128 + sg*8 + e] = K[b][it*128+r][g*8+e], sg=(g&8)|((g^r)&7)
// V image (b,it): dst[d*128 + sg*8 + j] = V[b][it*128+kg*8+j][d], sg=(kg&8)|((kg^d)&7)
__launch_bounds__(256, 4)
__global__ void prep_kernel(const float* __restrict__ K, const float* __restrict__ V,
                            short* __restrict__ KS, short* __restrict__ VS) {
    __shared__ short tile[128 * 136];   // [k][d] bf16, 16B-aligned rows
    const int t = threadIdx.x;
    const int blk = blockIdx.x;
    if (blk < 256) {
        const int b = blk >> 4, it = blk & 15;
        const float* src = K + ((size_t)b * BN + it * 128) * DD;
        short* dst = KS + (((size_t)b * 16 + it) << 14);
        #pragma unroll
        for (int i = 0; i < 8; ++i) {
            int gid = t + 256 * i;
            int r = gid >> 4, g = gid & 15;
            float4 f0 = *(const float4*)(src + r * DD + g * 8);
            float4 f1 = *(const float4*)(src + r * DD + g * 8 + 4);
            int sg = (g & 8) | ((g ^ r) & 7);
            *(bf8*)&dst[r * 128 + sg * 8] = cvt8(f0, f1);
        }
    } else {
        const int bb = blk - 256;
        const int b = bb >> 4, it = bb & 15;
        const float* src = V + ((size_t)b * BN + it * 128) * DD;
        short* dst = VS + (((size_t)b * 16 + it) << 14);
        #pragma unroll
        for (int i = 0; i < 8; ++i) {
            int gid = t + 256 * i;
            int r = gid >> 4, g = gid & 15;
            float4 f0 = *(const float4*)(src + r * DD + g * 8);
            float4 f1 = *(const float4*)(src + r * DD + g * 8 + 4);
            *(bf8*)&tile[r * 136 + g * 8] = cvt8(f0, f1);
        }
        __syncthreads();
        #pragma unroll
        for (int i = 0; i < 8; ++i) {
            int gid = t + 256 * i;
            int d = gid & 127, kg = gid >> 7;   // d varies across lanes -> conflict-free column reads
            bf8 w;
            #pragma unroll
            for (int j = 0; j < 8; ++j) w[j] = tile[(kg * 8 + j) * 136 + d];
            int sg = (kg & 8) | ((kg ^ d) & 7);
            *(bf8*)&dst[d * 128 + sg * 8] = w;
        }
    }
}

// ---------------- attention v2: DMA-staged, software-pipelined --------------
__launch_bounds__(256, 2)
__global__ void attn2(const float* __restrict__ Q,
                      const short* __restrict__ KS,
                      const short* __restrict__ VS,
                      const int* __restrict__ VL,
                      float* __restrict__ O) {
    __shared__ short sK[16384];   // 32 KB swizzled K image
    __shared__ short sV[16384];   // 32 KB swizzled V^T image
    __shared__ short sP[8192];    // 16 KB per-wave P

    const int tid  = threadIdx.x;
    const int wave = tid >> 6;
    const int lane = tid & 63;
    const int lw   = lane & 31;
    const int lh   = lane >> 5;
    const int rt   = wave & 1;   // q row-tile (32 rows)
    const int kh   = wave >> 1;  // key half (64 keys of the 128-key tile)

    const int L  = blockIdx.x;
    const int b  = (L & 7) | (((L >> 3) & 1) << 3);
    const int qt = L >> 4;
    const int q0 = qt * 64;

    const int vlen = VL[b];
    constexpr float SCL2 = 1.4426950408889634f * 0.08838834764831845f; // log2e/sqrt(128)

    float sclm[16];
    #pragma unroll
    for (int reg = 0; reg < 16; ++reg) {
        int row = (reg & 3) + 8 * (reg >> 2) + 4 * lh;
        sclm[reg] = (q0 + rt * 32 + row >= vlen) ? 0.0f : SCL2;
    }

    const short* kbase = KS + (((size_t)b * 16) << 14);
    const short* vbase = VS + (((size_t)b * 16) << 14);

    // issue sK(0) DMA before anything else
    dma_tile(sK, kbase, wave, lane);

    // Q fragments (A operand), direct f32 loads, once per block
    const size_t qoff = ((size_t)b * BN + q0 + rt * 32 + lw) * DD;
    bf8 qfrag[8];
    #pragma unroll
    for (int ks = 0; ks < 8; ++ks) {
        int d0 = ks * 16 + lh * 8;
        float4 f0 = *(const float4*)(Q + qoff + d0);
        float4 f1 = *(const float4*)(Q + qoff + d0 + 4);
        qfrag[ks] = cvt8(f0, f1);
    }

    f16v oacc[4] = {};
    float l[16];
    #pragma unroll
    for (int i = 0; i < 16; ++i) l[i] = 0.0f;

    const int pbase = wave * 2048;

    for (int it = 0; it < 16; ++it) {
        __syncthreads();                                   // sK(it) ready; sV(it-1) consumers done
        dma_tile(sV, vbase + ((size_t)it << 14), wave, lane);  // in flight during QK phase

        // ---- S = Q K^T (wave's 32 rows x 64 keys)
        f16v s0 = {}, s1 = {};
        #pragma unroll
        for (int ks = 0; ks < 8; ++ks) {
            int g  = ks * 2 + lh;
            int r0 = kh * 64 + lw;
            int sgA = (g & 8) | ((g ^ r0) & 7);
            bf8 b0 = *(const bf8*)&sK[r0 * 128 + sgA * 8];
            s0 = __builtin_amdgcn_mfma_f32_32x32x16_bf16(qfrag[ks], b0, s0, 0, 0, 0);
            int r1 = r0 + 32;
            int sgB = (g & 8) | ((g ^ r1) & 7);
            bf8 b1 = *(const bf8*)&sK[r1 * 128 + sgB * 8];
            s1 = __builtin_amdgcn_mfma_f32_32x32x16_bf16(qfrag[ks], b1, s1, 0, 0, 0);
        }

        // ---- p = exp2(s*sclm); accumulate l; P -> per-wave LDS (swizzled)
        #pragma unroll
        for (int reg = 0; reg < 16; ++reg) {
            float p0 = __builtin_amdgcn_exp2f(s0[reg] * sclm[reg]);
            float p1 = __builtin_amdgcn_exp2f(s1[reg] * sclm[reg]);
            l[reg] += p0 + p1;
            int row = (reg & 3) + 8 * (reg >> 2) + 4 * lh;
            int g0 = lw >> 3;
            sP[pbase + row * 64 + ((g0 ^ row) & 7) * 8 + (lw & 7)] = bf16rne(p0);
            int g1 = 4 + (lw >> 3);
            sP[pbase + row * 64 + ((g1 ^ row) & 7) * 8 + (lw & 7)] = bf16rne(p1);
        }

        __syncthreads();                                   // sV(it) ready; sK(it) consumers done
        if (it < 15)
            dma_tile(sK, kbase + ((size_t)(it + 1) << 14), wave, lane);  // in flight during PV

        // ---- O += P V (wave's own 64 keys)
        #pragma unroll
        for (int ks = 0; ks < 4; ++ks) {
            int gk  = ks * 2 + lh;
            int sgp = (gk ^ lw) & 7;
            bf8 pa = *(const bf8*)&sP[pbase + lw * 64 + sgp * 8];
            #pragma unroll
            for (int ot = 0; ot < 4; ++ot) {
                int d   = ot * 32 + lw;
                int gv  = kh * 8 + ks * 2 + lh;
                int sgv = (gv & 8) | ((gv ^ d) & 7);
                bf8 vb = *(const bf8*)&sV[d * 128 + sgv * 8];
                oacc[ot] = __builtin_amdgcn_mfma_f32_32x32x16_bf16(pa, vb, oacc[ot], 0, 0, 0);
            }
        }
    }

    __syncthreads();   // all PV reads of sV done before scratch reuse

    // ---- epilogue: combine key-halves
    float* oSh = (float*)sK;   // [rt][32][128] f32
    float* lSh = (float*)sV;   // [rt][16][64]  f32
    if (kh == 1) {
        #pragma unroll
        for (int ot = 0; ot < 4; ++ot) {
            #pragma unroll
            for (int reg = 0; reg < 16; ++reg) {
                int row = (reg & 3) + 8 * (reg >> 2) + 4 * lh;
                oSh[rt * 4096 + row * 128 + ot * 32 + lw] = oacc[ot][reg];
            }
        }
        #pragma unroll
        for (int reg = 0; reg < 16; ++reg)
            lSh[rt * 1024 + reg * 64 + lane] = l[reg];
    }
    __syncthreads();
    if (kh == 0) {
        #pragma unroll
        for (int reg = 0; reg < 16; ++reg)
            l[reg] += lSh[rt * 1024 + reg * 64 + lane];
        #pragma unroll
        for (int reg = 0; reg < 16; ++reg) {
            float t = l[reg];
            t += __shfl_xor(t, 1, 64);
            t += __shfl_xor(t, 2, 64);
            t += __shfl_xor(t, 4, 64);
            t += __shfl_xor(t, 8, 64);
            t += __shfl_xor(t, 16, 64);
            l[reg] = t;
        }
        #pragma unroll
        for (int ot = 0; ot < 4; ++ot) {
            #pragma unroll
            for (int reg = 0; reg < 16; ++reg) {
                int row = (reg & 3) + 8 * (reg >> 2) + 4 * lh;
                float val = oacc[ot][reg] + oSh[rt * 4096 + row * 128 + ot * 32 + lw];
                val /= l[reg];
                O[((size_t)b * BN + q0 + rt * 32 + row) * DD + ot * 32 + lw] = val;
            }
        }
    }
}

// ---------------- fallback v1 (no workspace needed) -------------------------
__launch_bounds__(256, 2)
__global__ void attn_v1(const float* __restrict__ Q,
                        const float* __restrict__ K,
                        const float* __restrict__ V,
                        const int* __restrict__ VL,
                        float* __restrict__ O) {
    __shared__ short sK[128 * 128];
    __shared__ short sV[128 * 128];
    __shared__ short sP[4 * 32 * 64];

    const int tid  = threadIdx.x;
    const int wave = tid >> 6;
    const int lane = tid & 63;
    const int lw   = lane & 31;
    const int lh   = lane >> 5;
    const int rt   = wave & 1;
    const int kh   = wave >> 1;

    const int L  = blockIdx.x;
    const int b  = (L & 7) | (((L >> 3) & 1) << 3);
    const int qt = L >> 4;
    const int q0 = qt * 64;
    const int vlen = VL[b];
    constexpr float SCL2 = 1.4426950408889634f * 0.08838834764831845f;

    float sclm[16];
    #pragma unroll
    for (int reg = 0; reg < 16; ++reg) {
        int row = (reg & 3) + 8 * (reg >> 2) + 4 * lh;
        sclm[reg] = (q0 + rt * 32 + row >= vlen) ? 0.0f : SCL2;
    }

    const size_t qoff = ((size_t)b * BN + q0 + rt * 32 + lw) * DD;
    bf8 qfrag[8];
    #pragma unroll
    for (int ks = 0; ks < 8; ++ks) {
        int d0 = ks * 16 + lh * 8;
        float4 f0 = *(const float4*)(Q + qoff + d0);
        float4 f1 = *(const float4*)(Q + qoff + d0 + 4);
        qfrag[ks] = cvt8(f0, f1);
    }

    f16v oacc[4] = {};
    float l[16];
    #pragma unroll
    for (int i = 0; i < 16; ++i) l[i] = 0.0f;
    const int pbase = wave * 2048;

    for (int it = 0; it < 16; ++it) {
        const int kb = it * 128;
        {
            int g  = tid & 15;
            int r0 = tid >> 4;
            #pragma unroll
            for (int i = 0; i < 8; ++i) {
                int r = r0 + 16 * i;
                const float* src = K + ((size_t)b * BN + kb + r) * DD + g * 8;
                float4 f0 = *(const float4*)(src);
                float4 f1 = *(const float4*)(src + 4);
                int sg = (g & 8) | ((g ^ r) & 7);
                *(bf8*)&sK[r * 128 + sg * 8] = cvt8(f0, f1);
            }
        }
        {
            int dq  = tid & 31;
            int kg0 = tid >> 5;
            #pragma unroll
            for (int i = 0; i < 2; ++i) {
                int kg = kg0 + 8 * i;
                float vr[32];
                #pragma unroll
                for (int j = 0; j < 8; ++j) {
                    float4 t = *(const float4*)(V + ((size_t)b * BN + kb + kg * 8 + j) * DD + dq * 4);
                    vr[j * 4 + 0] = t.x; vr[j * 4 + 1] = t.y;
                    vr[j * 4 + 2] = t.z; vr[j * 4 + 3] = t.w;
                }
                #pragma unroll
                for (int c = 0; c < 4; ++c) {
                    int d = dq * 4 + c;
                    bf8 w;
                    #pragma unroll
                    for (int j = 0; j < 8; ++j) w[j] = bf16rne(vr[j * 4 + c]);
                    int sg = (kg & 8) | ((kg ^ d) & 7);
                    *(bf8*)&sV[d * 128 + sg * 8] = w;
                }
            }
        }
        __syncthreads();

        f16v s0 = {}, s1 = {};
        #pragma unroll
        for (int ks = 0; ks < 8; ++ks) {
            int g  = ks * 2 + lh;
            int r0 = kh * 64 + lw;
            int sgA = (g & 8) | ((g ^ r0) & 7);
            bf8 b0 = *(const bf8*)&sK[r0 * 128 + sgA * 8];
            s0 = __builtin_amdgcn_mfma_f32_32x32x16_bf16(qfrag[ks], b0, s0, 0, 0, 0);
            int r1 = r0 + 32;
            int sgB = (g & 8) | ((g ^ r1) & 7);
            bf8 b1 = *(const bf8*)&sK[r1 * 128 + sgB * 8];
            s1 = __builtin_amdgcn_mfma_f32_32x32x16_bf16(qfrag[ks], b1, s1, 0, 0, 0);
        }

        #pragma unroll
        for (int reg = 0; reg < 16; ++reg) {
            float p0 = __builtin_amdgcn_exp2f(s0[reg] * sclm[reg]);
            float p1 = __builtin_amdgcn_exp2f(s1[reg] * sclm[reg]);
            l[reg] += p0 + p1;
            int row = (reg & 3) + 8 * (reg >> 2) + 4 * lh;
            int g0 = lw >> 3;
            sP[pbase + row * 64 + ((g0 ^ row) & 7) * 8 + (lw & 7)] = bf16rne(p0);
            int g1 = 4 + (lw >> 3);
            sP[pbase + row * 64 + ((g1 ^ row) & 7) * 8 + (lw & 7)] = bf16rne(p1);
        }

        #pragma unroll
        for (int ks = 0; ks < 4; ++ks) {
            int gk  = ks * 2 + lh;
            int sgp = (gk ^ lw) & 7;
            bf8 pa = *(const bf8*)&sP[pbase + lw * 64 + sgp * 8];
            #pragma unroll
            for (int ot = 0; ot < 4; ++ot) {
                int d   = ot * 32 + lw;
                int gv  = kh * 8 + ks * 2 + lh;
                int sgv = (gv & 8) | ((gv ^ d) & 7);
                bf8 vb = *(const bf8*)&sV[d * 128 + sgv * 8];
                oacc[ot] = __builtin_amdgcn_mfma_f32_32x32x16_bf16(pa, vb, oacc[ot], 0, 0, 0);
            }
        }
        __syncthreads();
    }

    float* oSh = (float*)sK;
    float* lSh = (float*)sV;
    if (kh == 1) {
        #pragma unroll
        for (int ot = 0; ot < 4; ++ot) {
            #pragma unroll
            for (int reg = 0; reg < 16; ++reg) {
                int row = (reg & 3) + 8 * (reg >> 2) + 4 * lh;
                oSh[rt * 4096 + row * 128 + ot * 32 + lw] = oacc[ot][reg];
            }
        }
        #pragma unroll
        for (int reg = 0; reg < 16; ++reg)
            lSh[rt * 1024 + reg * 64 + lane] = l[reg];
    }
    __syncthreads();
    if (kh == 0) {
        #pragma unroll
        for (int reg = 0; reg < 16; ++reg)
            l[reg] += lSh[rt * 1024 + reg * 64 + lane];
        #pragma unroll
        for (int reg = 0; reg < 16; ++reg) {
            float t = l[reg];
            t += __shfl_xor(t, 1, 64);
            t += __shfl_xor(t, 2, 64);
            t += __shfl_xor(t, 4, 64);
            t += __shfl_xor(t, 8, 64);
            t += __shfl_xor(t, 16, 64);
            l[reg] = t;
        }
        #pragma unroll
        for (int ot = 0; ot < 4; ++ot) {
            #pragma unroll
            for (int reg = 0; reg < 16; ++reg) {
                int row = (reg & 3) + 8 * (reg >> 2) + 4 * lh;
                float val = oacc[ot][reg] + oSh[rt * 4096 + row * 128 + ot * 32 + lw];
                val /= l[reg];
                O[((size_t)b * BN + q0 + rt * 32 + row) * DD + ot * 32 + lw] = val;
            }
        }
    }
}

extern "C" void kernel_launch(void* const* d_in, const int* in_sizes, int n_in,
                              void* d_out, int out_size, void* d_ws, size_t ws_size,
                              hipStream_t stream) {
    const float* Q  = (const float*)d_in[0];
    const float* K  = (const float*)d_in[1];
    const float* V  = (const float*)d_in[2];
    const int*   VL = (const int*)d_in[3];
    float* O = (float*)d_out;

    const size_t need = (size_t)2 * 16 * 16 * 16384 * sizeof(short);  // 16 MB
    if (ws_size >= need) {
        short* KS = (short*)d_ws;
        short* VS = KS + (size_t)16 * 16 * 16384;
        prep_kernel<<<512, 256, 0, stream>>>(K, V, KS, VS);
        attn2<<<512, 256, 0, stream>>>(Q, KS, VS, VL, O);
    } else {
        attn_v1<<<512, 256, 0, stream>>>(Q, K, V, VL, O);
    }
}